// Round 4
// baseline (564.769 us; speedup 1.0000x reference)
//
#include <hip/hip_runtime.h>
#include <math.h>

#define HID   128
#define MAXN  100000
#define MAXE  300000
#define EVT   4096
#define NNODE 20000
#define NEDGE 320000

typedef unsigned short u16;
typedef __attribute__((ext_vector_type(8))) short bf16x8;
typedef __attribute__((ext_vector_type(4))) float f32x4;

// ---------------- workspace layout (bytes) ----------------
// PERSIST (weights)
#define OFF_WIHB      0u            // 384*640 bf16
#define OFF_WHHB      491520u       // 384*128 bf16
#define OFF_WEB       589824u       // 128*256 bf16
#define OFF_WALLB     655360u       // 768*128 bf16
#define OFF_BALL      851968u       // 768 f32
#define BASE2         855040u
// EVENT arena
#define OFF_REP_SRC   (BASE2 + 0u)
#define OFF_REP_DST   (BASE2 + 400128u)
#define OFF_CNT_SRC   (BASE2 + 800256u)
#define OFF_CNT_DST   (BASE2 + 1200384u)
#define OFF_SUM_SRC   (BASE2 + 1600512u)    // 4096*640 f32
#define OFF_SUM_DST   (BASE2 + 12086272u)   // 4096*640 f32
#define OFF_XGB       (BASE2 + 22572032u)   // 8192*640 bf16
#define OFF_HG        (BASE2 + 33057792u)   // 8192*128 f32
#define OFF_HGB       (BASE2 + 37252096u)   // 8192*128 bf16
#define OFF_GI        (BASE2 + 39349248u)   // 8192*384 f32
#define OFF_GH        (BASE2 + 51932160u)   // 8192*384 f32  (end 64515072)
// NODE arena (aliases EVENT arena; event phase fully complete before writes)
#define OFF_XB        (BASE2 + 0u)          // 20000*128 bf16
#define OFF_QS        (BASE2 + 5120000u)    // 20000*512 f32 : q|skip|qet|qef
#define OFF_KVB       (BASE2 + 46080000u)   // 20000*256 bf16
#define OFF_DEG       (BASE2 + 56320000u)   // 20000 i32
#define OFF_OFFS      (BASE2 + 56400128u)   // 20001 i32
#define OFF_CURSOR    (BASE2 + 56480256u)   // 20000 i32
#define OFF_SORTED    (BASE2 + 56560384u)   // 320000 i32
#define OFF_SACCB     (BASE2 + 57840384u)   // 20000*256 bf16 (end 68080384)
// peak ~68.9 MB

__device__ __forceinline__ float sigmoidf_(float x) { return 1.f / (1.f + __expf(-x)); }
__device__ __forceinline__ u16 f2b(float f) {
    unsigned u = __float_as_uint(f);
    unsigned r = (u + 0x7fffu + ((u >> 16) & 1u)) >> 16;
    return (u16)r;
}
__device__ __forceinline__ float b2f(unsigned h) { return __uint_as_float(h << 16); }

// ---- fused weight prep: bf16 converts + Wall fold ----
__global__ __launch_bounds__(256) void k_prep(const float* __restrict__ w_ih, u16* __restrict__ w_ih_b,
                       const float* __restrict__ w_hh, u16* __restrict__ w_hh_b,
                       const float* __restrict__ we, u16* __restrict__ we_b,
                       const float* __restrict__ wq, const float* __restrict__ wk_,
                       const float* __restrict__ wv, const float* __restrict__ wskip,
                       const float* __restrict__ bq, const float* __restrict__ bk,
                       const float* __restrict__ bv, const float* __restrict__ bskip,
                       u16* __restrict__ Wallb, float* __restrict__ ball) {
    int b = blockIdx.x, t = threadIdx.x;
    if (b < 960) { int i = b * 256 + t; w_ih_b[i] = f2b(w_ih[i]); return; }
    if (b < 1152) { int i = (b - 960) * 256 + t; w_hh_b[i] = f2b(w_hh[i]); return; }
    if (b < 1280) { int i = (b - 1152) * 256 + t; we_b[i] = f2b(we[i]); return; }
    int idx = (b - 1280) * 256 + t;
    int row = idx >> 7, k = idx & 127;
    float v;
    if (row < 128)      v = wq[row * 128 + k];
    else if (row < 256) v = wk_[(row - 128) * 128 + k];
    else if (row < 384) v = wv[(row - 256) * 128 + k];
    else if (row < 512) v = wskip[(row - 384) * 128 + k];
    else {
        int j = row - 512;
        float a = 0.f;
        for (int q = 0; q < 128; q++) a += wq[q * 128 + k] * we[q * 256 + j];
        v = a;
    }
    Wallb[row * 128 + k] = f2b(v);
    if (k == 0) {
        float bb;
        if (row < 128)      bb = bq[row];
        else if (row < 256) bb = bk[row - 128];
        else if (row < 384) bb = bv[row - 256];
        else if (row < 512) bb = bskip[row - 384];
        else { int j = row - 512; float a = 0.f; for (int q = 0; q < 128; q++) a += bq[q] * we[q * 256 + j]; bb = a; }
        ball[row] = bb;
    }
}

// ---- rep/count tables ----
__global__ void k_tables(const int* __restrict__ src_ids, const int* __restrict__ dst_ids,
                         unsigned* rep_src, unsigned* rep_dst, int* cnt_src, int* cnt_dst) {
    int i = blockIdx.x * blockDim.x + threadIdx.x;
    if (i >= EVT) return;
    int s = src_ids[i], d = dst_ids[i];
    atomicMin(&rep_src[s], (unsigned)i);
    atomicAdd(&cnt_src[s], 1);
    atomicMin(&rep_dst[d], (unsigned)i);
    atomicAdd(&cnt_dst[d], 1);
}

// ---- zero only duplicate-id sum rows (replaces 21 MB memset) ----
__global__ void k_zerodup(const int* __restrict__ src_ids, const int* __restrict__ dst_ids,
                          const unsigned* __restrict__ rep_src, const unsigned* __restrict__ rep_dst,
                          const int* __restrict__ cnt_src, const int* __restrict__ cnt_dst,
                          float* sum_src, float* sum_dst) {
    int i = blockIdx.x, c = threadIdx.x;
    int sid = src_ids[i], did = dst_ids[i];
    if (cnt_src[sid] > 1 && rep_src[sid] == (unsigned)i) {
        float* p = sum_src + (size_t)i * 640;
#pragma unroll
        for (int h = 0; h < 5; ++h) p[h * 128 + c] = 0.f;
    }
    if (cnt_dst[did] > 1 && rep_dst[did] == (unsigned)i) {
        float* p = sum_dst + (size_t)i * 640;
#pragma unroll
        for (int h = 0; h < 5; ++h) p[h * 128 + c] = 0.f;
    }
}

// ---- messages + aggregation + Hg/Hgb side-write ----
__global__ void k_message(const int* __restrict__ et_ids, const int* __restrict__ src_ids,
                          const float* __restrict__ src_mask, const int* __restrict__ dst_ids,
                          const float* __restrict__ dst_mask, const int* __restrict__ ev_eids,
                          const float* __restrict__ ev_emb, const float* __restrict__ ev_mask,
                          const float* __restrict__ ev_ts, const float* __restrict__ memory,
                          const float* __restrict__ last_update, const float* __restrict__ time_w,
                          const float* __restrict__ time_b, const unsigned* __restrict__ rep_src,
                          const unsigned* __restrict__ rep_dst, const int* __restrict__ cnt_src,
                          const int* __restrict__ cnt_dst, float* sum_src, float* sum_dst,
                          float* __restrict__ Hg, u16* __restrict__ Hgb) {
    int i = blockIdx.x;
    int c = threadIdx.x;
    int et = et_ids[i];
    float sm = src_mask[i], dm = dst_mask[i], em = ev_mask[i], ts = ev_ts[i];
    int sid = src_ids[i], did = dst_ids[i], eid = ev_eids[i];
    float isnode = (et == 3 || et == 4) ? 1.f : 0.f;
    float rel = ts - last_update[eid] * dm;
    float tval = ts * isnode + rel * dm;
    float tse = __cosf(tval * time_w[c] + time_b[c]) * em;
    float typ = (float)et;
    float m_s = memory[(size_t)sid * HID + c];
    float m_d = memory[(size_t)did * HID + c];
    Hg[(size_t)i * HID + c] = m_s;
    Hgb[(size_t)i * HID + c] = f2b(m_s);
    Hg[(size_t)(EVT + i) * HID + c] = m_d;
    Hgb[(size_t)(EVT + i) * HID + c] = f2b(m_d);
    float sv = m_s * sm, dv = m_d * dm;
    float ev = ev_emb[(size_t)i * HID + c];
    float* ps = sum_src + (size_t)rep_src[sid] * 640;
    if (cnt_src[sid] == 1) {
        ps[c] = typ * em; ps[128 + c] = sv * em; ps[256 + c] = dv * em;
        ps[384 + c] = tse * em; ps[512 + c] = ev * em;
    } else {
        atomicAdd(ps + c, typ * em);
        atomicAdd(ps + 128 + c, sv * em);
        atomicAdd(ps + 256 + c, dv * em);
        atomicAdd(ps + 384 + c, tse * em);
        atomicAdd(ps + 512 + c, ev * em);
    }
    float* pd = sum_dst + (size_t)rep_dst[did] * 640;
    if (cnt_dst[did] == 1) {
        pd[c] = typ * dm; pd[128 + c] = dv * dm; pd[256 + c] = sv * dm;
        pd[384 + c] = tse * dm; pd[512 + c] = ev * dm;
    } else {
        atomicAdd(pd + c, typ * dm);
        atomicAdd(pd + 128 + c, dv * dm);
        atomicAdd(pd + 256 + c, sv * dm);
        atomicAdd(pd + 384 + c, tse * dm);
        atomicAdd(pd + 512 + c, ev * dm);
    }
}

// ---- gather means into Xg_b (8192 x 640 bf16) ----
__global__ void k_build_xg(const int* __restrict__ src_ids, const int* __restrict__ dst_ids,
                           const unsigned* __restrict__ rep_src, const unsigned* __restrict__ rep_dst,
                           const int* __restrict__ cnt_src, const int* __restrict__ cnt_dst,
                           const float* __restrict__ sum_src, const float* __restrict__ sum_dst,
                           u16* __restrict__ Xgb) {
    int r = blockIdx.x;
    int c = blockIdx.y * 128 + threadIdx.x;
    float v;
    if (r < EVT) {
        int id = src_ids[r];
        int cnt = cnt_src[id]; if (cnt < 1) cnt = 1;
        v = sum_src[(size_t)rep_src[id] * 640 + c] / (float)cnt;
    } else {
        int id = dst_ids[r - EVT];
        int cnt = cnt_dst[id]; if (cnt < 1) cnt = 1;
        v = sum_dst[(size_t)rep_dst[id] * 640 + c] / (float)cnt;
    }
    Xgb[(size_t)r * 640 + c] = f2b(v);
}

// ---- MFMA bf16 GEMM; special=1 -> QS/KVb split epilogue ----
__global__ __launch_bounds__(256) void k_gemm_mfma(const u16* __restrict__ A,
                                                   const u16* __restrict__ W,
                                                   const float* __restrict__ bias,
                                                   float* __restrict__ C, int ldc,
                                                   u16* __restrict__ KVb,
                                                   int M, int N, int K, int acc, int special) {
    __shared__ u16 Als[128 * 40];
    __shared__ u16 Wls[128 * 40];
    int tid = threadIdx.x;
    int bm = blockIdx.x * 128, bn = blockIdx.y * 128;
    int wave = tid >> 6, lane = tid & 63;
    int wm = (wave & 1) * 64, wn = (wave >> 1) * 64;
    int l15 = lane & 15, quad = lane >> 4;
    f32x4 accf[4][4] = {};
    for (int k0 = 0; k0 < K; k0 += 32) {
#pragma unroll
        for (int h = 0; h < 2; ++h) {
            int ch = tid + h * 256;
            int row = ch >> 2, kc = (ch & 3) * 8;
            int gr = bm + row;
            float4 av = make_float4(0.f, 0.f, 0.f, 0.f);
            if (gr < M) av = *(const float4*)(A + (size_t)gr * K + k0 + kc);
            *(float4*)&Als[row * 40 + kc] = av;
            int wr = bn + row;
            float4 wv_ = *(const float4*)(W + (size_t)wr * K + k0 + kc);
            *(float4*)&Wls[row * 40 + kc] = wv_;
        }
        __syncthreads();
        bf16x8 af[4], bfr[4];
#pragma unroll
        for (int r = 0; r < 4; ++r)
            af[r] = *(const bf16x8*)&Als[(wm + r * 16 + l15) * 40 + quad * 8];
#pragma unroll
        for (int c2 = 0; c2 < 4; ++c2)
            bfr[c2] = *(const bf16x8*)&Wls[(wn + c2 * 16 + l15) * 40 + quad * 8];
#pragma unroll
        for (int r = 0; r < 4; ++r)
#pragma unroll
            for (int c2 = 0; c2 < 4; ++c2)
                accf[r][c2] = __builtin_amdgcn_mfma_f32_16x16x32_bf16(af[r], bfr[c2], accf[r][c2], 0, 0, 0);
        __syncthreads();
    }
    int y = blockIdx.y;
    int qsb = -1, kvbase = -1;
    if (special) {
        qsb = (y == 0) ? 0 : (y == 3) ? 128 : (y == 4) ? 256 : (y == 5) ? 384 : -1;
        kvbase = (y == 1) ? 0 : (y == 2) ? 128 : -1;
    }
#pragma unroll
    for (int r = 0; r < 4; ++r) {
#pragma unroll
        for (int c2 = 0; c2 < 4; ++c2) {
            int colw = wn + c2 * 16 + l15;          // 0..127 within tile
            int ncol = bn + colw;                   // global col (bias index)
            float bv = bias ? bias[ncol] : 0.f;
#pragma unroll
            for (int reg = 0; reg < 4; ++reg) {
                int mrow = bm + wm + r * 16 + quad * 4 + reg;
                if (mrow >= M) continue;
                float v = accf[r][c2][reg] + bv;
                if (special) {
                    if (qsb >= 0) C[(size_t)mrow * 512 + qsb + colw] = v;
                    if (kvbase >= 0) KVb[(size_t)mrow * 256 + kvbase + colw] = f2b(v);
                } else {
                    if (acc) v += C[(size_t)mrow * ldc + ncol];
                    C[(size_t)mrow * ldc + ncol] = v;
                }
            }
        }
    }
}

// ---- GRU gate combine + direct scatter into memory ----
__global__ void k_gruscat(const float* __restrict__ Gi, const float* __restrict__ Gh,
                          const float* __restrict__ Hg, const int* __restrict__ ids,
                          int roff, float* __restrict__ memory) {
    int b = blockIdx.x, c = threadIdx.x;
    int r = b + roff;
    const float* gi = Gi + (size_t)r * 384;
    const float* gh = Gh + (size_t)r * 384;
    float rg = sigmoidf_(gi[c] + gh[c]);
    float z  = sigmoidf_(gi[128 + c] + gh[128 + c]);
    float n  = tanhf(gi[256 + c] + rg * gh[256 + c]);
    float h  = Hg[(size_t)r * HID + c];
    memory[(size_t)ids[b] * HID + c] = (1.f - z) * n + z * h;
}

__global__ void k_x(const int* __restrict__ node_ids, const float* __restrict__ nf,
                    const float* __restrict__ memory, u16* __restrict__ Xb) {
    int p = blockIdx.x, c = threadIdx.x;
    int nid = node_ids[p];
    Xb[(size_t)p * HID + c] = f2b(nf[(size_t)nid * HID + c] + memory[(size_t)nid * HID + c]);
}

// ---- dst-degree histogram ----
__global__ void k_deg(const int* __restrict__ eidx, int* __restrict__ deg) {
    int j = blockIdx.x * blockDim.x + threadIdx.x;
    if (j >= NEDGE) return;
    atomicAdd(&deg[eidx[NEDGE + j]], 1);
}

// ---- single-block exclusive scan over 20000 degrees ----
__global__ __launch_bounds__(1024) void k_scan(const int* __restrict__ deg,
                                               int* __restrict__ offs, int* __restrict__ cursor) {
    __shared__ int part[1024];
    int t = threadIdx.x;
    int base = t * 20;
    int loc[20]; int s = 0;
    for (int i = 0; i < 20; i++) { int idx = base + i; int v = (idx < NNODE) ? deg[idx] : 0; loc[i] = s; s += v; }
    part[t] = s; __syncthreads();
    for (int dgap = 1; dgap < 1024; dgap <<= 1) {
        int v = (t >= dgap) ? part[t - dgap] : 0;
        __syncthreads();
        part[t] += v;
        __syncthreads();
    }
    int excl = (t == 0) ? 0 : part[t - 1];
    for (int i = 0; i < 20; i++) { int idx = base + i; if (idx < NNODE) { int o = excl + loc[i]; offs[idx] = o; cursor[idx] = o; } }
    if (t == 1023) offs[NNODE] = part[1023];
}

__global__ void k_sortscat(const int* __restrict__ eidx, int* __restrict__ cursor,
                           int* __restrict__ sorted) {
    int j = blockIdx.x * blockDim.x + threadIdx.x;
    if (j >= NEDGE) return;
    int d = eidx[NEDGE + j];
    int pos = atomicAdd(&cursor[d], 1);
    sorted[pos] = j;
}

// ---- fused per-node attention: 8-edge batched online softmax ----
__global__ __launch_bounds__(256) void k_node(const float* __restrict__ QS,
        const u16* __restrict__ KVb, const int* __restrict__ offs,
        const int* __restrict__ sorted, const int* __restrict__ eidx,
        const int* __restrict__ edge_ids, const float* __restrict__ last_update,
        const float* __restrict__ time_w, const float* __restrict__ time_b,
        const float* __restrict__ ef, const int* __restrict__ tptr,
        float* __restrict__ out, u16* __restrict__ saccb) {
    int wave = threadIdx.x >> 6, lane = threadIdx.x & 63;
    int n = blockIdx.x * 4 + wave;
    int c = 2 * lane;
    const float* base = QS + (size_t)n * 512;
    float2 qd   = *(const float2*)(base + c);
    float2 skip = *(const float2*)(base + 128 + c);
    float2 qet  = *(const float2*)(base + 256 + c);
    float2 qef  = *(const float2*)(base + 384 + c);
    float2 tw   = *(const float2*)(time_w + c);
    float2 tb   = *(const float2*)(time_b + c);
    float tf = (float)(*tptr);
    int start = offs[n], end = offs[n + 1];
    int deg = end - start;
    if (deg == 0) {
        *(float2*)(out + (size_t)n * HID + c) = skip;
        *(unsigned*)(saccb + (size_t)n * 256 + c) = 0u;
        *(unsigned*)(saccb + (size_t)n * 256 + 128 + c) = 0u;
        return;
    }
    float m = -1e30f, l_ = 0.f;
    float va0 = 0.f, va1 = 0.f, s00 = 0.f, s01 = 0.f, s10 = 0.f, s11 = 0.f;
    for (int cb = start; cb < end; cb += 64) {
        int cnt = end - cb; if (cnt > 64) cnt = 64;
        int s_l = 0, eid_l = 0; float rt_l = 0.f;
        if (lane < cnt) {
            int j = sorted[cb + lane];
            s_l = eidx[j];
            eid_l = edge_ids[j];
            rt_l = tf - last_update[eid_l];
        }
        for (int e0 = 0; e0 < cnt; e0 += 8) {
            float pv[8], cv0[8], cv1[8], vx[8], vy[8], ex[8], ey[8];
#pragma unroll
            for (int i = 0; i < 8; ++i) {
                int idx = e0 + i;
                int sel = (idx < cnt) ? idx : e0;
                int s   = __shfl(s_l, sel, 64);
                int eid = __shfl(eid_l, sel, 64);
                float rt = __shfl(rt_l, sel, 64);
                unsigned kvp = *(const unsigned*)(KVb + (size_t)s * 256 + c);
                unsigned vvp = *(const unsigned*)(KVb + (size_t)s * 256 + 128 + c);
                float2 ev = *(const float2*)(ef + (size_t)eid * HID + c);
                float k0f = b2f(kvp & 0xffffu), k1f = b2f(kvp >> 16);
                vx[i] = b2f(vvp & 0xffffu); vy[i] = b2f(vvp >> 16);
                cv0[i] = __cosf(rt * tw.x + tb.x);
                cv1[i] = __cosf(rt * tw.y + tb.y);
                ex[i] = ev.x; ey[i] = ev.y;
                pv[i] = qd.x * k0f + qd.y * k1f + qet.x * cv0[i] + qet.y * cv1[i]
                      + qef.x * ev.x + qef.y * ev.y;
            }
#pragma unroll
            for (int msk = 32; msk > 0; msk >>= 1) {
#pragma unroll
                for (int i = 0; i < 8; ++i) pv[i] += __shfl_xor(pv[i], msk, 64);
            }
            float al[8];
#pragma unroll
            for (int i = 0; i < 8; ++i)
                al[i] = (e0 + i < cnt) ? pv[i] * 0.08838834764831845f : -1e30f;
            float gm = al[0];
#pragma unroll
            for (int i = 1; i < 8; ++i) gm = fmaxf(gm, al[i]);
            if (gm > m) {
                float fac = __expf(m - gm);
                l_ *= fac; va0 *= fac; va1 *= fac;
                s00 *= fac; s01 *= fac; s10 *= fac; s11 *= fac;
                m = gm;
            }
#pragma unroll
            for (int i = 0; i < 8; ++i) {
                float w = __expf(al[i] - m);
                l_ += w;
                va0 += w * vx[i]; va1 += w * vy[i];
                s00 += w * cv0[i]; s01 += w * cv1[i];
                s10 += w * ex[i]; s11 += w * ey[i];
            }
        }
    }
    float inv = 1.f / fmaxf(l_, 1e-16f);
    float2 o; o.x = va0 * inv + skip.x; o.y = va1 * inv + skip.y;
    *(float2*)(out + (size_t)n * HID + c) = o;
    unsigned p0 = (unsigned)f2b(s00 * inv) | ((unsigned)f2b(s01 * inv) << 16);
    unsigned p1 = (unsigned)f2b(s10 * inv) | ((unsigned)f2b(s11 * inv) << 16);
    *(unsigned*)(saccb + (size_t)n * 256 + c) = p0;
    *(unsigned*)(saccb + (size_t)n * 256 + 128 + c) = p1;
}

extern "C" void kernel_launch(void* const* d_in, const int* in_sizes, int n_in,
                              void* d_out, int out_size, void* d_ws, size_t ws_size,
                              hipStream_t stream) {
    const int*   et_ids        = (const int*)d_in[0];
    const int*   src_ids       = (const int*)d_in[1];
    const float* src_mask      = (const float*)d_in[2];
    const int*   dst_ids       = (const int*)d_in[3];
    const float* dst_mask      = (const float*)d_in[4];
    const int*   ev_eids       = (const int*)d_in[5];
    const float* ev_emb        = (const float*)d_in[6];
    const float* ev_mask       = (const float*)d_in[7];
    const float* ev_ts         = (const float*)d_in[8];
    const int*   node_ids      = (const int*)d_in[9];
    const int*   edge_ids      = (const int*)d_in[10];
    const int*   edge_index    = (const int*)d_in[11];
    const int*   tptr          = (const int*)d_in[12];
    float*       memory        = (float*)d_in[13];
    const float* last_update   = (const float*)d_in[14];
    const float* node_features = (const float*)d_in[15];
    const float* edge_features = (const float*)d_in[16];
    const float* time_w        = (const float*)d_in[17];
    const float* time_b        = (const float*)d_in[18];
    const float* w_ih          = (const float*)d_in[19];
    const float* w_hh          = (const float*)d_in[20];
    const float* b_ih          = (const float*)d_in[21];
    const float* b_hh          = (const float*)d_in[22];
    const float* wq            = (const float*)d_in[23];
    const float* bq            = (const float*)d_in[24];
    const float* wk            = (const float*)d_in[25];
    const float* bk            = (const float*)d_in[26];
    const float* wv            = (const float*)d_in[27];
    const float* bv            = (const float*)d_in[28];
    const float* we            = (const float*)d_in[29];
    const float* wskip         = (const float*)d_in[30];
    const float* bskip         = (const float*)d_in[31];
    float* out = (float*)d_out;
    char*  wsb = (char*)d_ws;

    u16*   w_ih_b  = (u16*)(wsb + OFF_WIHB);
    u16*   w_hh_b  = (u16*)(wsb + OFF_WHHB);
    u16*   we_b    = (u16*)(wsb + OFF_WEB);
    u16*   Wallb   = (u16*)(wsb + OFF_WALLB);
    float* ball    = (float*)(wsb + OFF_BALL);
    unsigned* rep_src = (unsigned*)(wsb + OFF_REP_SRC);
    unsigned* rep_dst = (unsigned*)(wsb + OFF_REP_DST);
    int*   cnt_src = (int*)(wsb + OFF_CNT_SRC);
    int*   cnt_dst = (int*)(wsb + OFF_CNT_DST);
    float* sum_src = (float*)(wsb + OFF_SUM_SRC);
    float* sum_dst = (float*)(wsb + OFF_SUM_DST);
    u16*   Xgb     = (u16*)(wsb + OFF_XGB);
    float* Hg      = (float*)(wsb + OFF_HG);
    u16*   Hgb     = (u16*)(wsb + OFF_HGB);
    float* Gi      = (float*)(wsb + OFF_GI);
    float* Gh      = (float*)(wsb + OFF_GH);
    u16*   Xb      = (u16*)(wsb + OFF_XB);
    float* QS      = (float*)(wsb + OFF_QS);
    u16*   KVb     = (u16*)(wsb + OFF_KVB);
    int*   deg     = (int*)(wsb + OFF_DEG);
    int*   offs    = (int*)(wsb + OFF_OFFS);
    int*   cursor  = (int*)(wsb + OFF_CURSOR);
    int*   sorted  = (int*)(wsb + OFF_SORTED);
    u16*   saccb   = (u16*)(wsb + OFF_SACCB);

    // ---- weight prep ----
    k_prep<<<1664, 256, 0, stream>>>(w_ih, w_ih_b, w_hh, w_hh_b, we, we_b,
                                     wq, wk, wv, wskip, bq, bk, bv, bskip, Wallb, ball);

    // ---- event phase ----
    hipMemsetAsync(wsb + OFF_REP_SRC, 0xFF, 800256, stream);
    hipMemsetAsync(wsb + OFF_CNT_SRC, 0, 800256, stream);
    k_tables<<<16, 256, 0, stream>>>(src_ids, dst_ids, rep_src, rep_dst, cnt_src, cnt_dst);
    k_zerodup<<<EVT, 128, 0, stream>>>(src_ids, dst_ids, rep_src, rep_dst, cnt_src, cnt_dst,
                                       sum_src, sum_dst);
    k_message<<<EVT, 128, 0, stream>>>(et_ids, src_ids, src_mask, dst_ids, dst_mask, ev_eids,
                                       ev_emb, ev_mask, ev_ts, memory, last_update, time_w, time_b,
                                       rep_src, rep_dst, cnt_src, cnt_dst, sum_src, sum_dst,
                                       Hg, Hgb);
    k_build_xg<<<dim3(2 * EVT, 5), 128, 0, stream>>>(src_ids, dst_ids, rep_src, rep_dst,
                                                     cnt_src, cnt_dst, sum_src, sum_dst, Xgb);
    k_gemm_mfma<<<dim3(64, 3), 256, 0, stream>>>(Xgb, w_ih_b, b_ih, Gi, 384, nullptr, 2 * EVT, 384, 640, 0, 0);
    k_gemm_mfma<<<dim3(64, 3), 256, 0, stream>>>(Hgb, w_hh_b, b_hh, Gh, 384, nullptr, 2 * EVT, 384, 128, 0, 0);
    k_gruscat<<<EVT, 128, 0, stream>>>(Gi, Gh, Hg, src_ids, 0, memory);     // src first
    k_gruscat<<<EVT, 128, 0, stream>>>(Gi, Gh, Hg, dst_ids, EVT, memory);   // dst overrides

    // ---- node phase ----
    k_x<<<NNODE, 128, 0, stream>>>(node_ids, node_features, memory, Xb);
    k_gemm_mfma<<<dim3(157, 6), 256, 0, stream>>>(Xb, Wallb, ball, QS, 512, KVb, NNODE, 768, 128, 0, 1);
    hipMemsetAsync(wsb + OFF_DEG, 0, 80128, stream);
    k_deg<<<1250, 256, 0, stream>>>(edge_index, deg);
    k_scan<<<1, 1024, 0, stream>>>(deg, offs, cursor);
    k_sortscat<<<1250, 256, 0, stream>>>(edge_index, cursor, sorted);
    k_node<<<NNODE / 4, 256, 0, stream>>>(QS, KVb, offs, sorted, edge_index, edge_ids,
                                          last_update, time_w, time_b, edge_features, tptr,
                                          out, saccb);
    k_gemm_mfma<<<dim3(157, 1), 256, 0, stream>>>(saccb, we_b, nullptr, out, 128, nullptr, NNODE, 128, 256, 1, 0);
}